// Round 19
// baseline (435.919 us; speedup 1.0000x reference)
//
#include <hip/hip_runtime.h>

#define NGRAPH 2048

typedef __attribute__((ext_vector_type(8))) short bf16x8;
typedef __attribute__((ext_vector_type(4))) float f32x4;
typedef __attribute__((ext_vector_type(8))) _Float16 h16x8;
typedef __attribute__((ext_vector_type(2))) _Float16 h16x2;

__device__ inline unsigned short bf16_rne(float f) {
  union { float f; unsigned u; } c; c.f = f;
  unsigned u = c.u + 0x7fffu + ((c.u >> 16) & 1u);
  return (unsigned short)(u >> 16);
}
__device__ inline float bf16_to_f32(unsigned short h) {
  union { float f; unsigned u; } c; c.u = ((unsigned)h) << 16;
  return c.f;
}

// ================= single-pass scan (ticket + decoupled lookback, unsigned flags) =================
__global__ __launch_bounds__(256) void scan_onepass(
    const int* __restrict__ deg, int* __restrict__ rowstart, int* __restrict__ cursor,
    unsigned* __restrict__ scanst, int N, int E, int nchunk)
{
  __shared__ int tmp[256];
  __shared__ int sh_chunk;
  __shared__ int sh_exc;
  int tid = threadIdx.x;
  if (tid == 0) sh_chunk = (int)atomicAdd(&scanst[nchunk], 1u);
  __syncthreads();
  int cb = sh_chunk;
  int i = cb * 256 + tid;
  int v = (i < N) ? deg[i] : 0;
  tmp[tid] = v;
  __syncthreads();
#pragma unroll
  for (int off = 1; off < 256; off <<= 1) {
    int t = (tid >= off) ? tmp[tid - off] : 0;
    __syncthreads();
    tmp[tid] += t;
    __syncthreads();
  }
  int aggregate = tmp[255];

  if (tid == 0) {
    const unsigned VMASK = (1u << 30) - 1u;
    if (cb == 0) {
      atomicExch(&scanst[0], (2u << 30) | (unsigned)aggregate);
      sh_exc = 0;
    } else {
      atomicExch(&scanst[cb], (1u << 30) | (unsigned)aggregate);
      int excv = 0;
      int j = cb - 1;
      while (j >= 0) {
        unsigned s;
        do { s = atomicAdd(&scanst[j], 0u); } while ((s >> 30) == 0u);
        excv += (int)(s & VMASK);
        if ((s >> 30) == 2u) break;
        --j;
      }
      sh_exc = excv;
      atomicExch(&scanst[cb], (2u << 30) | (unsigned)(excv + aggregate));
    }
  }
  __syncthreads();
  int exc = sh_exc;
  if (i < N) {
    int rs = exc + tmp[tid] - v;
    rowstart[i] = rs;
    cursor[i] = rs;
  }
  if (cb == nchunk - 1 && tid == 0) rowstart[N] = E;
}

__global__ __launch_bounds__(256) void fill_eidx(
    const int* __restrict__ src, const int* __restrict__ dst,
    int* __restrict__ cursor, int* __restrict__ eidx, int E)
{
  int e = blockIdx.x * 256 + threadIdx.x;
  if (e >= E) return;
  int d = dst[e];
  int pos = atomicAdd(&cursor[d], 1);
  eidx[pos] = src[e];
}

// ====== merged: degree hist + weight repack + x pad(fp16) + zero(bnstat) + graph boundaries ======
struct WPs {
  const float* w[5];
  unsigned short* hi[5];
  unsigned short* lo[5];
};
__global__ __launch_bounds__(256) void prep_hist(
    WPs p, const float* __restrict__ x, _Float16* __restrict__ x8h, int N,
    const int* __restrict__ dst, int* __restrict__ deg, int E,
    const int* __restrict__ batch, int* __restrict__ gstart,
    float* __restrict__ bnstat)
{
  int g = blockIdx.x * 256 + threadIdx.x;
  if (g < E) {
    atomicAdd(&deg[dst[g]], 1);
    return;
  }
  int q = g - E;
  if (q < 5 * 16384) {
    int m = q >> 14;
    int j = q & 16383;
    int c = j >> 3, e = j & 7;
    int t = c >> 8, kc = (c >> 6) & 3, lane = c & 63;
    int n = t * 16 + (lane & 15);
    int k = kc * 32 + (lane >> 4) * 8 + e;
    float w = p.w[m][k * 128 + n];
    unsigned short h = bf16_rne(w);
    p.hi[m][j] = h;
    p.lo[m][j] = bf16_rne(w - bf16_to_f32(h));
    return;
  }
  q -= 5 * 16384;
  if (q < N * 8) {
    int v = q >> 3, j = q & 7;
    x8h[q] = (_Float16)((j < 7) ? x[(long)v * 7 + j] : 0.f);
    return;
  }
  q -= N * 8;
  if (q < 256) { bnstat[q] = 0.f; return; }
  q -= 256;
  if (q < N) {
    int b = batch[q];
    int bp = (q > 0) ? batch[q - 1] : -1;
    for (int gg = bp + 1; gg <= b; ++gg) gstart[gg] = q;
    if (q == N - 1)
      for (int gg = b + 1; gg <= NGRAPH; ++gg) gstart[gg] = N;
  }
}

// ================= standalone gather (barrier-free, max occupancy) =================
// 16 lanes per node, lane sub loads column chunk sub*8 (16 B); z row written coalesced.
__global__ __launch_bounds__(256) void gather_h(
    const _Float16* __restrict__ H, const int* __restrict__ rowstart,
    const int* __restrict__ eidx, _Float16* __restrict__ Z, int M)
{
  long t = (long)blockIdx.x * 256 + threadIdx.x;
  int v = (int)(t >> 4);
  if (v >= M) return;
  int sub = (int)(t & 15);
  const _Float16* Hc = H + sub * 8;
  h16x8 sv = *(const h16x8*)&Hc[(long)v * 128];
  float a0[8], a1[8];
#pragma unroll
  for (int j = 0; j < 8; ++j) { a0[j] = (float)sv[j]; a1[j] = 0.f; }
  int e0 = rowstart[v], e1 = rowstart[v + 1];
  int e = e0;
  for (; e + 4 <= e1; e += 4) {
    int s0 = eidx[e], s1 = eidx[e + 1], s2 = eidx[e + 2], s3 = eidx[e + 3];
    h16x8 h0 = *(const h16x8*)&Hc[(long)s0 * 128];
    h16x8 h1 = *(const h16x8*)&Hc[(long)s1 * 128];
    h16x8 h2 = *(const h16x8*)&Hc[(long)s2 * 128];
    h16x8 h3 = *(const h16x8*)&Hc[(long)s3 * 128];
#pragma unroll
    for (int j = 0; j < 8; ++j) {
      a0[j] += (float)h0[j] + (float)h2[j];
      a1[j] += (float)h1[j] + (float)h3[j];
    }
  }
  for (; e + 2 <= e1; e += 2) {
    int s0 = eidx[e], s1 = eidx[e + 1];
    h16x8 h0 = *(const h16x8*)&Hc[(long)s0 * 128];
    h16x8 h1 = *(const h16x8*)&Hc[(long)s1 * 128];
#pragma unroll
    for (int j = 0; j < 8; ++j) {
      a0[j] += (float)h0[j];
      a1[j] += (float)h1[j];
    }
  }
  if (e < e1) {
    int s = eidx[e];
    h16x8 h = *(const h16x8*)&Hc[(long)s * 128];
#pragma unroll
    for (int j = 0; j < 8; ++j) a1[j] += (float)h[j];
  }
  h16x8 zo;
#pragma unroll
  for (int j = 0; j < 8; ++j) zo[j] = (_Float16)(a0[j] + a1[j]);
  *(h16x8*)&Z[(long)v * 128 + sub * 8] = zo;
}

// ---- split-precision GEMM pass over a 64x128 fp16 LDS tile (chunk-rot swizzle) ----
__device__ inline void mfma_pass(
    const _Float16* __restrict__ zbuf,
    const unsigned short* __restrict__ Whi, const unsigned short* __restrict__ Wlo,
    int rw, int m16, int quad, int lane, f32x4 acc[8])
{
  int r = rw + m16;
  const _Float16* zrow = &zbuf[r * 128];
#pragma unroll
  for (int kc = 0; kc < 4; ++kc) {
    int cidx = kc * 4 + quad;
    h16x8 zh = *(const h16x8*)&zrow[((cidx + r) & 15) * 8];
    bf16x8 ah, al;
#pragma unroll
    for (int j = 0; j < 8; ++j) {
      float f = (float)zh[j];
      unsigned short h = bf16_rne(f);
      ah[j] = (short)h;
      al[j] = (short)bf16_rne(f - bf16_to_f32(h));
    }
#pragma unroll
    for (int t = 0; t < 8; ++t) {
      long cb = ((t * 4 + kc) * 64 + lane) * 8;
      bf16x8 bh = *(const bf16x8*)&Whi[cb];
      bf16x8 bl = *(const bf16x8*)&Wlo[cb];
      acc[t] = __builtin_amdgcn_mfma_f32_16x16x32_bf16(ah, bh, acc[t], 0, 0, 0);
      acc[t] = __builtin_amdgcn_mfma_f32_16x16x32_bf16(ah, bl, acc[t], 0, 0, 0);
      acc[t] = __builtin_amdgcn_mfma_f32_16x16x32_bf16(al, bh, acc[t], 0, 0, 0);
    }
  }
}

// ================= MLP-only layer kernel: z (global, fp16) -> relu(..W1..)-> relu(..W2..) -> H =================
__global__ __launch_bounds__(256, 8) void mlp2(
    const _Float16* __restrict__ Zin,
    const unsigned short* __restrict__ W1hi, const unsigned short* __restrict__ W1lo,
    const float* __restrict__ B1,
    const unsigned short* __restrict__ W2hi, const unsigned short* __restrict__ W2lo,
    const float* __restrict__ B2,
    _Float16* __restrict__ Out, int M)
{
  __shared__ _Float16 zbuf[64 * 128];   // 16 KB
  int tid = threadIdx.x;
  int rbase = blockIdx.x * 64;

  // coalesced load z tile into swizzled LDS
  {
    int sub = tid & 15;
    int ng = tid >> 4;
#pragma unroll
    for (int it = 0; it < 4; ++it) {
      int r = it * 16 + ng;
      int v = rbase + r;
      int vc = (v < M) ? v : (M - 1);
      h16x8 zi = *(const h16x8*)&Zin[(long)vc * 128 + sub * 8];
      *(h16x8*)&zbuf[r * 128 + ((sub + r) & 15) * 8] = zi;
    }
  }
  __syncthreads();

  int lane = tid & 63;
  int wv = tid >> 6;
  int m16 = lane & 15;
  int quad = lane >> 4;
  int rw = wv * 16;

  f32x4 acc[8];
#pragma unroll
  for (int t = 0; t < 8; ++t) acc[t] = (f32x4){0.f, 0.f, 0.f, 0.f};
  mfma_pass(zbuf, W1hi, W1lo, rw, m16, quad, lane, acc);

  float bias[8];
#pragma unroll
  for (int t = 0; t < 8; ++t) bias[t] = B1[t * 16 + m16];

  __syncthreads();
#pragma unroll
  for (int i = 0; i < 4; ++i) {
    int r = rw + quad * 4 + i;
#pragma unroll
    for (int t = 0; t < 8; ++t) {
      int col = t * 16 + m16;
      int cidx = col >> 3;
      zbuf[r * 128 + ((cidx + r) & 15) * 8 + (col & 7)] =
          (_Float16)fmaxf(acc[t][i] + bias[t], 0.f);
    }
  }
  __syncthreads();

#pragma unroll
  for (int t = 0; t < 8; ++t) acc[t] = (f32x4){0.f, 0.f, 0.f, 0.f};
  mfma_pass(zbuf, W2hi, W2lo, rw, m16, quad, lane, acc);

#pragma unroll
  for (int t = 0; t < 8; ++t) bias[t] = B2[t * 16 + m16];

#pragma unroll
  for (int i = 0; i < 4; ++i) {
    int r = rbase + rw + quad * 4 + i;
    if (r < M) {
#pragma unroll
      for (int t = 0; t < 8; ++t) {
        float o = fmaxf(acc[t][i] + bias[t], 0.f);
        Out[(long)r * 128 + t * 16 + m16] = (_Float16)o;
      }
    }
  }
}

// ================= fused layer 1: gather(x8h fp16) + K=7 GEMM + MFMA GEMM =================
__global__ __launch_bounds__(256, 8) void fused_l1(
    const _Float16* __restrict__ x8h, const int* __restrict__ rowstart,
    const int* __restrict__ eidx,
    const float* __restrict__ W1, const float* __restrict__ B1,
    const unsigned short* __restrict__ W2hi, const unsigned short* __restrict__ W2lo,
    const float* __restrict__ B2, _Float16* __restrict__ Out, int M)
{
  __shared__ _Float16 ybuf[64 * 128];
  __shared__ float z1s[64][8];
  int tid = threadIdx.x;
  int rbase = blockIdx.x * 64;

  {
    int node = tid >> 2, sub = tid & 3;
    int v = rbase + node;
    int vc = (v < M) ? v : (M - 1);
    float a[8];
    if (sub == 0) {
      h16x8 sv = *(const h16x8*)&x8h[(long)vc * 8];
#pragma unroll
      for (int j = 0; j < 8; ++j) a[j] = (float)sv[j];
    } else {
#pragma unroll
      for (int j = 0; j < 8; ++j) a[j] = 0.f;
    }
    int e0 = rowstart[vc], e1 = rowstart[vc + 1];
    int e = e0 + sub;
    for (; e + 4 < e1; e += 8) {
      int s0 = eidx[e], s1 = eidx[e + 4];
      h16x8 h0 = *(const h16x8*)&x8h[(long)s0 * 8];
      h16x8 h1 = *(const h16x8*)&x8h[(long)s1 * 8];
#pragma unroll
      for (int j = 0; j < 8; ++j) a[j] += (float)h0[j] + (float)h1[j];
    }
    if (e < e1) {
      int s = eidx[e];
      h16x8 h = *(const h16x8*)&x8h[(long)s * 8];
#pragma unroll
      for (int j = 0; j < 8; ++j) a[j] += (float)h[j];
    }
#pragma unroll
    for (int j = 0; j < 8; ++j) {
      a[j] += __shfl_xor(a[j], 1, 64);
      a[j] += __shfl_xor(a[j], 2, 64);
    }
    if (sub == 0) {
#pragma unroll
      for (int j = 0; j < 8; ++j) z1s[node][j] = a[j];
    }
  }
  __syncthreads();

  {
    int c = tid & 127;
    int cidx = c >> 3, celt = c & 7;
    int rh0 = (tid >> 7) * 32;
    float w1r[7];
#pragma unroll
    for (int k = 0; k < 7; ++k) w1r[k] = W1[k * 128 + c];
    float b1 = B1[c];
#pragma unroll 4
    for (int rr = 0; rr < 32; ++rr) {
      int r = rh0 + rr;
      const float* zp = z1s[r];
      float a = b1;
#pragma unroll
      for (int k = 0; k < 7; ++k) a += zp[k] * w1r[k];
      ybuf[r * 128 + ((cidx + r) & 15) * 8 + celt] = (_Float16)fmaxf(a, 0.f);
    }
  }
  __syncthreads();

  int lane = tid & 63;
  int wv = tid >> 6;
  int m16 = lane & 15;
  int quad = lane >> 4;
  int rw = wv * 16;

  f32x4 acc[8];
#pragma unroll
  for (int t = 0; t < 8; ++t) acc[t] = (f32x4){0.f, 0.f, 0.f, 0.f};
  mfma_pass(ybuf, W2hi, W2lo, rw, m16, quad, lane, acc);

  float bias[8];
#pragma unroll
  for (int t = 0; t < 8; ++t) bias[t] = B2[t * 16 + m16];

#pragma unroll
  for (int i = 0; i < 4; ++i) {
    int r = rbase + rw + quad * 4 + i;
    if (r < M) {
#pragma unroll
      for (int t = 0; t < 8; ++t) {
        float o = fmaxf(acc[t][i] + bias[t], 0.f);
        Out[(long)r * 128 + t * 16 + m16] = (_Float16)o;
      }
    }
  }
}

// ================= pooling: one block per graph, zero atomics =================
__global__ __launch_bounds__(256) void pool_direct(
    const _Float16* __restrict__ H1, const _Float16* __restrict__ H2,
    const _Float16* __restrict__ H3, const int* __restrict__ gstart,
    float* __restrict__ P, float* __restrict__ cnt)
{
  int g = blockIdx.x;
  int s = gstart[g], e = gstart[g + 1];
  int tid = threadIdx.x;
  if (tid == 0) cnt[g] = (float)(e - s);
  if (tid >= 192) return;
  int cp = tid * 2;
  const _Float16* A = (cp < 128) ? H1 : ((cp < 256) ? H2 : H3);
  int c = cp & 127;
  float ax = 0.f, ay = 0.f, bx = 0.f, by = 0.f;
  int i = s;
  for (; i + 2 <= e; i += 2) {
    h16x2 v0 = *(const h16x2*)&A[(long)i * 128 + c];
    h16x2 v1 = *(const h16x2*)&A[(long)(i + 1) * 128 + c];
    ax += (float)v0[0]; ay += (float)v0[1];
    bx += (float)v1[0]; by += (float)v1[1];
  }
  if (i < e) {
    h16x2 v0 = *(const h16x2*)&A[(long)i * 128 + c];
    ax += (float)v0[0]; ay += (float)v0[1];
  }
  float2 o = {ax + bx, ay + by};
  *(float2*)&P[(long)g * 384 + cp] = o;
}

// ================= JK: G = P(2048x384) @ W(384x128) + cnt*B  (1024 blocks) =================
__global__ __launch_bounds__(256) void jk_gemm(
    const float* __restrict__ P, const float* __restrict__ cnt,
    const float* __restrict__ W, const float* __restrict__ B,
    float* __restrict__ G)
{
  __shared__ float pl[768];
  int tid = threadIdx.x, blk = blockIdx.x;
  for (int o = tid; o < 768; o += 256) pl[o] = P[(long)blk * 768 + o];
  __syncthreads();
  int rr = tid >> 7;
  int col = tid & 127;
  int row = blk * 2 + rr;
  float acc = cnt[row] * B[col];
#pragma unroll 8
  for (int k = 0; k < 384; ++k)
    acc += pl[rr * 384 + k] * W[k * 128 + col];
  G[(long)row * 128 + col] = acc;
}

// ================= classifier GEMM + BN stat atomics =================
__global__ __launch_bounds__(256) void gemm_bn(
    const float* __restrict__ Z,
    const float* __restrict__ W, const float* __restrict__ B,
    float* __restrict__ Out, float* __restrict__ bnstat, int M)
{
  __shared__ float wlds[128 * 128];
  int tid = threadIdx.x;
  {
    const float4* Ws = (const float4*)W;
    float4* Wd = (float4*)wlds;
#pragma unroll
    for (int i = 0; i < 16; ++i) Wd[i * 256 + tid] = Ws[i * 256 + tid];
  }
  __syncthreads();

  int rg = tid >> 5;
  int c0 = (tid & 31) * 4;
  int rbase = blockIdx.x * 64 + rg * 8;

  float acc[8][4];
#pragma unroll
  for (int i = 0; i < 8; ++i)
#pragma unroll
    for (int j = 0; j < 4; ++j) acc[i][j] = 0.f;

#pragma unroll 2
  for (int kc = 0; kc < 128; kc += 4) {
    float zv[8][4];
#pragma unroll
    for (int i = 0; i < 8; ++i) {
      float4 z = *(const float4*)&Z[(long)(rbase + i) * 128 + kc];
      zv[i][0] = z.x; zv[i][1] = z.y; zv[i][2] = z.z; zv[i][3] = z.w;
    }
#pragma unroll
    for (int kk = 0; kk < 4; ++kk) {
      float4 w = *(const float4*)&wlds[(kc + kk) * 128 + c0];
#pragma unroll
      for (int i = 0; i < 8; ++i) {
        float z = zv[i][kk];
        acc[i][0] += z * w.x; acc[i][1] += z * w.y;
        acc[i][2] += z * w.z; acc[i][3] += z * w.w;
      }
    }
  }

  float4 b = *(const float4*)&B[c0];
  float s[4] = {0.f, 0.f, 0.f, 0.f};
  float s2[4] = {0.f, 0.f, 0.f, 0.f};
#pragma unroll
  for (int i = 0; i < 8; ++i) {
    float4 o;
    o.x = acc[i][0] + b.x; o.y = acc[i][1] + b.y;
    o.z = acc[i][2] + b.z; o.w = acc[i][3] + b.w;
    *(float4*)&Out[(long)(rbase + i) * 128 + c0] = o;
    s[0] += o.x; s[1] += o.y; s[2] += o.z; s[3] += o.w;
    s2[0] += o.x * o.x; s2[1] += o.y * o.y; s2[2] += o.z * o.z; s2[3] += o.w * o.w;
  }
#pragma unroll
  for (int j = 0; j < 4; ++j) {
    atomicAdd(&bnstat[c0 + j], s[j]);
    atomicAdd(&bnstat[128 + c0 + j], s2[j]);
  }
}

// ================= BN apply + relu + final [128x2] matmul =================
__global__ __launch_bounds__(256) void bn_final(
    const float* __restrict__ ZC, const float* __restrict__ bnstat,
    const float* __restrict__ gma, const float* __restrict__ bta,
    const float* __restrict__ W2, const float* __restrict__ B2, float* __restrict__ out)
{
  __shared__ float scl[128], shf[128];
  int tid = threadIdx.x;
  if (tid < 128) {
    float mu = bnstat[tid] * (1.f / NGRAPH);
    float var = bnstat[128 + tid] * (1.f / NGRAPH) - mu * mu;
    float rs = rsqrtf(var + 1e-5f);
    float sc = gma[tid] * rs;
    scl[tid] = sc;
    shf[tid] = bta[tid] - mu * sc;
  }
  __syncthreads();
  int g = blockIdx.x * 256 + tid;
  if (g >= NGRAPH) return;
  float a0 = B2[0], a1 = B2[1];
#pragma unroll 4
  for (int h = 0; h < 128; ++h) {
    float zn = ZC[(long)g * 128 + h] * scl[h] + shf[h];
    zn = fmaxf(zn, 0.f);
    a0 += zn * W2[2 * h];
    a1 += zn * W2[2 * h + 1];
  }
  out[2 * g] = a0;
  out[2 * g + 1] = a1;
}

extern "C" void kernel_launch(void* const* d_in, const int* in_sizes, int n_in,
                              void* d_out, int out_size, void* d_ws, size_t ws_size,
                              hipStream_t stream)
{
  const float* x    = (const float*)d_in[0];
  const int*   ei   = (const int*)d_in[1];
  const int*   batch = (const int*)d_in[3];
  const float* g1w1 = (const float*)d_in[4];  const float* g1b1 = (const float*)d_in[5];
  const float* g1w2 = (const float*)d_in[6];  const float* g1b2 = (const float*)d_in[7];
  const float* g2w1 = (const float*)d_in[8];  const float* g2b1 = (const float*)d_in[9];
  const float* g2w2 = (const float*)d_in[10]; const float* g2b2 = (const float*)d_in[11];
  const float* g3w1 = (const float*)d_in[12]; const float* g3b1 = (const float*)d_in[13];
  const float* g3w2 = (const float*)d_in[14]; const float* g3b2 = (const float*)d_in[15];
  const float* jkw  = (const float*)d_in[16]; const float* jkb  = (const float*)d_in[17];
  const float* c1w  = (const float*)d_in[18]; const float* c1b  = (const float*)d_in[19];
  const float* bng  = (const float*)d_in[20]; const float* bnb  = (const float*)d_in[21];
  const float* c2w  = (const float*)d_in[22]; const float* c2b  = (const float*)d_in[23];

  const int N = in_sizes[3];
  const int E = in_sizes[1] / 2;
  const int* src = ei;
  const int* dst = ei + E;

  char* w = (char*)d_ws;
  auto alloc = [&](size_t bytes) {
    char* p = w;
    w += (bytes + 255) & ~(size_t)255;
    return p;
  };
  _Float16* hA = (_Float16*)alloc((size_t)N * 128 * 2);   // layer-3 out
  _Float16* hB = (_Float16*)alloc((size_t)N * 128 * 2);   // layer-2 out
  _Float16* hC = (_Float16*)alloc((size_t)N * 128 * 2);   // layer-1 out
  _Float16* zt = (_Float16*)alloc((size_t)N * 128 * 2);   // gather scratch
  _Float16* x8h = (_Float16*)alloc((size_t)N * 8 * 2);
  float* P       = (float*)alloc((size_t)NGRAPH * 384 * 4);
  float* cnt     = (float*)alloc((size_t)NGRAPH * 4);
  float* bnstat  = (float*)alloc(256 * 4);
  float* gbuf = (float*)alloc((size_t)NGRAPH * 128 * 4);
  float* zc   = (float*)alloc((size_t)NGRAPH * 128 * 4);
  // deg, scanst contiguous -> one memset
  int* deg      = (int*)alloc((size_t)N * 4);
  unsigned* scanst = (unsigned*)alloc((size_t)1024 * 4);
  int* cursor   = (int*)alloc((size_t)N * 4);
  int* rowstart = (int*)alloc((size_t)(N + 1) * 4);
  int* eidx     = (int*)alloc((size_t)E * 4);
  int* gstart   = (int*)alloc((size_t)(NGRAPH + 1) * 4);
  unsigned short* wtbuf = (unsigned short*)alloc((size_t)5 * 2 * 16384 * 2);

  unsigned short* WThi[5];
  unsigned short* WTlo[5];
  for (int m = 0; m < 5; ++m) {
    WThi[m] = wtbuf + (size_t)m * 2 * 16384;
    WTlo[m] = WThi[m] + 16384;
  }

  const int nchunk = (N + 255) / 256;
  const int eb = (E + 255) / 256;

  // ---- memset deg+scanst (contiguous allocs incl. padding) ----
  hipMemsetAsync(deg, 0, (size_t)((char*)(scanst + 1024) - (char*)deg), stream);

  // ---- merged hist + weight prep + x pad(fp16) + zero(bnstat) + graph boundaries ----
  {
    WPs p;
    p.w[0] = g1w2; p.w[1] = g2w1; p.w[2] = g2w2; p.w[3] = g3w1; p.w[4] = g3w2;
    for (int m = 0; m < 5; ++m) { p.hi[m] = WThi[m]; p.lo[m] = WTlo[m]; }
    int total = E + 5 * 16384 + N * 8 + 256 + N;
    prep_hist<<<(total + 255) / 256, 256, 0, stream>>>(p, x, x8h, N, dst, deg, E,
                                                       batch, gstart, bnstat);
  }

  // ---- single-pass scan (writes rowstart + cursor) + fill ----
  scan_onepass<<<nchunk, 256, 0, stream>>>(deg, rowstart, cursor, scanst, N, E, nchunk);
  fill_eidx<<<eb, 256, 0, stream>>>(src, dst, cursor, eidx, E);

  const int fBlocks = (N + 63) / 64;
  const int gBlocks = (int)(((long)N * 16 + 255) / 256);

  // ---- layer 1 (gather fused; x is tiny/L2-resident) ----
  fused_l1<<<fBlocks, 256, 0, stream>>>(x8h, rowstart, eidx, g1w1, g1b1,
      WThi[0], WTlo[0], g1b2, hC, N);

  // ---- layer 2: standalone gather + MLP ----
  gather_h<<<gBlocks, 256, 0, stream>>>(hC, rowstart, eidx, zt, N);
  mlp2<<<fBlocks, 256, 0, stream>>>(zt, WThi[1], WTlo[1], g2b1,
      WThi[2], WTlo[2], g2b2, hB, N);

  // ---- layer 3: standalone gather + MLP ----
  gather_h<<<gBlocks, 256, 0, stream>>>(hB, rowstart, eidx, zt, N);
  mlp2<<<fBlocks, 256, 0, stream>>>(zt, WThi[3], WTlo[3], g3b1,
      WThi[4], WTlo[4], g3b2, hA, N);

  // ---- pooling: one block per graph, no atomics ----
  pool_direct<<<NGRAPH, 256, 0, stream>>>(hC, hB, hA, gstart, P, cnt);

  // ---- head ----
  jk_gemm<<<NGRAPH / 2, 256, 0, stream>>>(P, cnt, jkw, jkb, gbuf);
  gemm_bn<<<NGRAPH / 64, 256, 0, stream>>>(gbuf, c1w, c1b, zc, bnstat, NGRAPH);
  bn_final<<<(NGRAPH + 255) / 256, 256, 0, stream>>>(zc, bnstat, bng, bnb, c2w, c2b, (float*)d_out);
}

// Round 20
// 407.258 us; speedup vs baseline: 1.0704x; 1.0704x over previous
//
#include <hip/hip_runtime.h>

#define NGRAPH 2048

typedef __attribute__((ext_vector_type(4))) float f32x4;
typedef __attribute__((ext_vector_type(8))) _Float16 h16x8;
typedef __attribute__((ext_vector_type(2))) _Float16 h16x2;

// ================= single-pass scan (ticket + decoupled lookback, unsigned flags) =================
__global__ __launch_bounds__(256) void scan_onepass(
    const int* __restrict__ deg, int* __restrict__ rowstart, int* __restrict__ cursor,
    unsigned* __restrict__ scanst, int N, int E, int nchunk)
{
  __shared__ int tmp[256];
  __shared__ int sh_chunk;
  __shared__ int sh_exc;
  int tid = threadIdx.x;
  if (tid == 0) sh_chunk = (int)atomicAdd(&scanst[nchunk], 1u);
  __syncthreads();
  int cb = sh_chunk;
  int i = cb * 256 + tid;
  int v = (i < N) ? deg[i] : 0;
  tmp[tid] = v;
  __syncthreads();
#pragma unroll
  for (int off = 1; off < 256; off <<= 1) {
    int t = (tid >= off) ? tmp[tid - off] : 0;
    __syncthreads();
    tmp[tid] += t;
    __syncthreads();
  }
  int aggregate = tmp[255];

  if (tid == 0) {
    const unsigned VMASK = (1u << 30) - 1u;
    if (cb == 0) {
      atomicExch(&scanst[0], (2u << 30) | (unsigned)aggregate);
      sh_exc = 0;
    } else {
      atomicExch(&scanst[cb], (1u << 30) | (unsigned)aggregate);
      int excv = 0;
      int j = cb - 1;
      while (j >= 0) {
        unsigned s;
        do { s = atomicAdd(&scanst[j], 0u); } while ((s >> 30) == 0u);
        excv += (int)(s & VMASK);
        if ((s >> 30) == 2u) break;
        --j;
      }
      sh_exc = excv;
      atomicExch(&scanst[cb], (2u << 30) | (unsigned)(excv + aggregate));
    }
  }
  __syncthreads();
  int exc = sh_exc;
  if (i < N) {
    int rs = exc + tmp[tid] - v;
    rowstart[i] = rs;
    cursor[i] = rs;
  }
  if (cb == nchunk - 1 && tid == 0) rowstart[N] = E;
}

__global__ __launch_bounds__(256) void fill_eidx(
    const int* __restrict__ src, const int* __restrict__ dst,
    int* __restrict__ cursor, int* __restrict__ eidx, int E)
{
  int e = blockIdx.x * 256 + threadIdx.x;
  if (e >= E) return;
  int d = dst[e];
  int pos = atomicAdd(&cursor[d], 1);
  eidx[pos] = src[e];
}

// ====== merged: degree hist + weight repack(fp16 hi/lo) + x pad(fp16) + zero(bnstat) + graph bounds ======
struct WPs {
  const float* w[5];
  _Float16* hi[5];
  _Float16* lo[5];
};
__global__ __launch_bounds__(256) void prep_hist(
    WPs p, const float* __restrict__ x, _Float16* __restrict__ x8h, int N,
    const int* __restrict__ dst, int* __restrict__ deg, int E,
    const int* __restrict__ batch, int* __restrict__ gstart,
    float* __restrict__ bnstat)
{
  int g = blockIdx.x * 256 + threadIdx.x;
  if (g < E) {
    atomicAdd(&deg[dst[g]], 1);
    return;
  }
  int q = g - E;
  if (q < 5 * 16384) {
    int m = q >> 14;
    int j = q & 16383;
    int c = j >> 3, e = j & 7;
    int t = c >> 8, kc = (c >> 6) & 3, lane = c & 63;
    int n = t * 16 + (lane & 15);
    int k = kc * 32 + (lane >> 4) * 8 + e;
    float w = p.w[m][k * 128 + n];
    _Float16 h = (_Float16)w;
    p.hi[m][j] = h;
    p.lo[m][j] = (_Float16)(w - (float)h);
    return;
  }
  q -= 5 * 16384;
  if (q < N * 8) {
    int v = q >> 3, j = q & 7;
    x8h[q] = (_Float16)((j < 7) ? x[(long)v * 7 + j] : 0.f);
    return;
  }
  q -= N * 8;
  if (q < 256) { bnstat[q] = 0.f; return; }
  q -= 256;
  if (q < N) {
    int b = batch[q];
    int bp = (q > 0) ? batch[q - 1] : -1;
    for (int gg = bp + 1; gg <= b; ++gg) gstart[gg] = q;
    if (q == N - 1)
      for (int gg = b + 1; gg <= NGRAPH; ++gg) gstart[gg] = N;
  }
}

// ---- f16-MFMA GEMM pass: activations exact fp16 from LDS, weights fp16 hi+lo ----
__device__ inline void mfma_pass(
    const _Float16* __restrict__ zbuf,
    const _Float16* __restrict__ Whi, const _Float16* __restrict__ Wlo,
    int rw, int m16, int quad, int lane, f32x4 acc[8])
{
  int r = rw + m16;
  const _Float16* zrow = &zbuf[r * 128];
#pragma unroll
  for (int kc = 0; kc < 4; ++kc) {
    int cidx = kc * 4 + quad;
    h16x8 ah = *(const h16x8*)&zrow[((cidx + r) & 15) * 8];
#pragma unroll
    for (int t = 0; t < 8; ++t) {
      long cb = ((t * 4 + kc) * 64 + lane) * 8;
      h16x8 bh = *(const h16x8*)&Whi[cb];
      h16x8 bl = *(const h16x8*)&Wlo[cb];
      acc[t] = __builtin_amdgcn_mfma_f32_16x16x32_f16(ah, bh, acc[t], 0, 0, 0);
      acc[t] = __builtin_amdgcn_mfma_f32_16x16x32_f16(ah, bl, acc[t], 0, 0, 0);
    }
  }
}

// ================= fused GIN layer (layers 2,3): gather + MLP1 + MLP2 =================
__global__ __launch_bounds__(256, 8) void fused_gin(
    const _Float16* __restrict__ H, const int* __restrict__ rowstart,
    const int* __restrict__ eidx,
    const _Float16* __restrict__ W1hi, const _Float16* __restrict__ W1lo,
    const float* __restrict__ B1,
    const _Float16* __restrict__ W2hi, const _Float16* __restrict__ W2lo,
    const float* __restrict__ B2,
    _Float16* __restrict__ Out, int M)
{
  __shared__ _Float16 zbuf[64 * 128];   // 16 KB
  int tid = threadIdx.x;
  int rbase = blockIdx.x * 64;

  {
    int sub = tid & 15;
    int ng = tid >> 4;
    const _Float16* Hc = H + sub * 8;
#pragma unroll
    for (int it = 0; it < 4; ++it) {
      int r = it * 16 + ng;
      int v = rbase + r;
      int vc = (v < M) ? v : (M - 1);
      h16x8 sv = *(const h16x8*)&Hc[(long)vc * 128];
      float a0[8], a1[8];
#pragma unroll
      for (int j = 0; j < 8; ++j) { a0[j] = (float)sv[j]; a1[j] = 0.f; }
      int e0 = rowstart[vc], e1 = rowstart[vc + 1];
      int e = e0;
      for (; e + 4 <= e1; e += 4) {
        int s0 = eidx[e], s1 = eidx[e + 1], s2 = eidx[e + 2], s3 = eidx[e + 3];
        h16x8 h0 = *(const h16x8*)&Hc[(long)s0 * 128];
        h16x8 h1 = *(const h16x8*)&Hc[(long)s1 * 128];
        h16x8 h2 = *(const h16x8*)&Hc[(long)s2 * 128];
        h16x8 h3 = *(const h16x8*)&Hc[(long)s3 * 128];
#pragma unroll
        for (int j = 0; j < 8; ++j) {
          a0[j] += (float)h0[j] + (float)h2[j];
          a1[j] += (float)h1[j] + (float)h3[j];
        }
      }
      for (; e + 2 <= e1; e += 2) {
        int s0 = eidx[e], s1 = eidx[e + 1];
        h16x8 h0 = *(const h16x8*)&Hc[(long)s0 * 128];
        h16x8 h1 = *(const h16x8*)&Hc[(long)s1 * 128];
#pragma unroll
        for (int j = 0; j < 8; ++j) {
          a0[j] += (float)h0[j];
          a1[j] += (float)h1[j];
        }
      }
      if (e < e1) {
        int s = eidx[e];
        h16x8 h = *(const h16x8*)&Hc[(long)s * 128];
#pragma unroll
        for (int j = 0; j < 8; ++j) a1[j] += (float)h[j];
      }
      h16x8 zo;
#pragma unroll
      for (int j = 0; j < 8; ++j) zo[j] = (_Float16)(a0[j] + a1[j]);
      *(h16x8*)&zbuf[r * 128 + ((sub + r) & 15) * 8] = zo;
    }
  }
  __syncthreads();

  int lane = tid & 63;
  int wv = tid >> 6;
  int m16 = lane & 15;
  int quad = lane >> 4;
  int rw = wv * 16;

  f32x4 acc[8];
#pragma unroll
  for (int t = 0; t < 8; ++t) acc[t] = (f32x4){0.f, 0.f, 0.f, 0.f};
  mfma_pass(zbuf, W1hi, W1lo, rw, m16, quad, lane, acc);

  float bias[8];
#pragma unroll
  for (int t = 0; t < 8; ++t) bias[t] = B1[t * 16 + m16];

  __syncthreads();
#pragma unroll
  for (int i = 0; i < 4; ++i) {
    int r = rw + quad * 4 + i;
#pragma unroll
    for (int t = 0; t < 8; ++t) {
      int col = t * 16 + m16;
      int cidx = col >> 3;
      zbuf[r * 128 + ((cidx + r) & 15) * 8 + (col & 7)] =
          (_Float16)fmaxf(acc[t][i] + bias[t], 0.f);
    }
  }
  __syncthreads();

#pragma unroll
  for (int t = 0; t < 8; ++t) acc[t] = (f32x4){0.f, 0.f, 0.f, 0.f};
  mfma_pass(zbuf, W2hi, W2lo, rw, m16, quad, lane, acc);

#pragma unroll
  for (int t = 0; t < 8; ++t) bias[t] = B2[t * 16 + m16];

#pragma unroll
  for (int i = 0; i < 4; ++i) {
    int r = rbase + rw + quad * 4 + i;
    if (r < M) {
#pragma unroll
      for (int t = 0; t < 8; ++t) {
        float o = fmaxf(acc[t][i] + bias[t], 0.f);
        Out[(long)r * 128 + t * 16 + m16] = (_Float16)o;
      }
    }
  }
}

// ================= fused layer 1: gather(x8h fp16) + K=7 GEMM + MFMA GEMM =================
__global__ __launch_bounds__(256, 8) void fused_l1(
    const _Float16* __restrict__ x8h, const int* __restrict__ rowstart,
    const int* __restrict__ eidx,
    const float* __restrict__ W1, const float* __restrict__ B1,
    const _Float16* __restrict__ W2hi, const _Float16* __restrict__ W2lo,
    const float* __restrict__ B2, _Float16* __restrict__ Out, int M)
{
  __shared__ _Float16 ybuf[64 * 128];
  __shared__ float z1s[64][8];
  int tid = threadIdx.x;
  int rbase = blockIdx.x * 64;

  {
    int node = tid >> 2, sub = tid & 3;
    int v = rbase + node;
    int vc = (v < M) ? v : (M - 1);
    float a[8];
    if (sub == 0) {
      h16x8 sv = *(const h16x8*)&x8h[(long)vc * 8];
#pragma unroll
      for (int j = 0; j < 8; ++j) a[j] = (float)sv[j];
    } else {
#pragma unroll
      for (int j = 0; j < 8; ++j) a[j] = 0.f;
    }
    int e0 = rowstart[vc], e1 = rowstart[vc + 1];
    int e = e0 + sub;
    for (; e + 4 < e1; e += 8) {
      int s0 = eidx[e], s1 = eidx[e + 4];
      h16x8 h0 = *(const h16x8*)&x8h[(long)s0 * 8];
      h16x8 h1 = *(const h16x8*)&x8h[(long)s1 * 8];
#pragma unroll
      for (int j = 0; j < 8; ++j) a[j] += (float)h0[j] + (float)h1[j];
    }
    if (e < e1) {
      int s = eidx[e];
      h16x8 h = *(const h16x8*)&x8h[(long)s * 8];
#pragma unroll
      for (int j = 0; j < 8; ++j) a[j] += (float)h[j];
    }
#pragma unroll
    for (int j = 0; j < 8; ++j) {
      a[j] += __shfl_xor(a[j], 1, 64);
      a[j] += __shfl_xor(a[j], 2, 64);
    }
    if (sub == 0) {
#pragma unroll
      for (int j = 0; j < 8; ++j) z1s[node][j] = a[j];
    }
  }
  __syncthreads();

  {
    int c = tid & 127;
    int cidx = c >> 3, celt = c & 7;
    int rh0 = (tid >> 7) * 32;
    float w1r[7];
#pragma unroll
    for (int k = 0; k < 7; ++k) w1r[k] = W1[k * 128 + c];
    float b1 = B1[c];
#pragma unroll 4
    for (int rr = 0; rr < 32; ++rr) {
      int r = rh0 + rr;
      const float* zp = z1s[r];
      float a = b1;
#pragma unroll
      for (int k = 0; k < 7; ++k) a += zp[k] * w1r[k];
      ybuf[r * 128 + ((cidx + r) & 15) * 8 + celt] = (_Float16)fmaxf(a, 0.f);
    }
  }
  __syncthreads();

  int lane = tid & 63;
  int wv = tid >> 6;
  int m16 = lane & 15;
  int quad = lane >> 4;
  int rw = wv * 16;

  f32x4 acc[8];
#pragma unroll
  for (int t = 0; t < 8; ++t) acc[t] = (f32x4){0.f, 0.f, 0.f, 0.f};
  mfma_pass(ybuf, W2hi, W2lo, rw, m16, quad, lane, acc);

  float bias[8];
#pragma unroll
  for (int t = 0; t < 8; ++t) bias[t] = B2[t * 16 + m16];

#pragma unroll
  for (int i = 0; i < 4; ++i) {
    int r = rbase + rw + quad * 4 + i;
    if (r < M) {
#pragma unroll
      for (int t = 0; t < 8; ++t) {
        float o = fmaxf(acc[t][i] + bias[t], 0.f);
        Out[(long)r * 128 + t * 16 + m16] = (_Float16)o;
      }
    }
  }
}

// ================= pooling: one block per graph, zero atomics =================
__global__ __launch_bounds__(256) void pool_direct(
    const _Float16* __restrict__ H1, const _Float16* __restrict__ H2,
    const _Float16* __restrict__ H3, const int* __restrict__ gstart,
    float* __restrict__ P, float* __restrict__ cnt)
{
  int g = blockIdx.x;
  int s = gstart[g], e = gstart[g + 1];
  int tid = threadIdx.x;
  if (tid == 0) cnt[g] = (float)(e - s);
  if (tid >= 192) return;
  int cp = tid * 2;
  const _Float16* A = (cp < 128) ? H1 : ((cp < 256) ? H2 : H3);
  int c = cp & 127;
  float ax = 0.f, ay = 0.f, bx = 0.f, by = 0.f;
  int i = s;
  for (; i + 2 <= e; i += 2) {
    h16x2 v0 = *(const h16x2*)&A[(long)i * 128 + c];
    h16x2 v1 = *(const h16x2*)&A[(long)(i + 1) * 128 + c];
    ax += (float)v0[0]; ay += (float)v0[1];
    bx += (float)v1[0]; by += (float)v1[1];
  }
  if (i < e) {
    h16x2 v0 = *(const h16x2*)&A[(long)i * 128 + c];
    ax += (float)v0[0]; ay += (float)v0[1];
  }
  float2 o = {ax + bx, ay + by};
  *(float2*)&P[(long)g * 384 + cp] = o;
}

// ================= JK: G = P(2048x384) @ W(384x128) + cnt*B  (1024 blocks) =================
__global__ __launch_bounds__(256) void jk_gemm(
    const float* __restrict__ P, const float* __restrict__ cnt,
    const float* __restrict__ W, const float* __restrict__ B,
    float* __restrict__ G)
{
  __shared__ float pl[768];
  int tid = threadIdx.x, blk = blockIdx.x;
  for (int o = tid; o < 768; o += 256) pl[o] = P[(long)blk * 768 + o];
  __syncthreads();
  int rr = tid >> 7;
  int col = tid & 127;
  int row = blk * 2 + rr;
  float acc = cnt[row] * B[col];
#pragma unroll 8
  for (int k = 0; k < 384; ++k)
    acc += pl[rr * 384 + k] * W[k * 128 + col];
  G[(long)row * 128 + col] = acc;
}

// ================= classifier GEMM + BN stat atomics =================
__global__ __launch_bounds__(256) void gemm_bn(
    const float* __restrict__ Z,
    const float* __restrict__ W, const float* __restrict__ B,
    float* __restrict__ Out, float* __restrict__ bnstat, int M)
{
  __shared__ float wlds[128 * 128];
  int tid = threadIdx.x;
  {
    const float4* Ws = (const float4*)W;
    float4* Wd = (float4*)wlds;
#pragma unroll
    for (int i = 0; i < 16; ++i) Wd[i * 256 + tid] = Ws[i * 256 + tid];
  }
  __syncthreads();

  int rg = tid >> 5;
  int c0 = (tid & 31) * 4;
  int rbase = blockIdx.x * 64 + rg * 8;

  float acc[8][4];
#pragma unroll
  for (int i = 0; i < 8; ++i)
#pragma unroll
    for (int j = 0; j < 4; ++j) acc[i][j] = 0.f;

#pragma unroll 2
  for (int kc = 0; kc < 128; kc += 4) {
    float zv[8][4];
#pragma unroll
    for (int i = 0; i < 8; ++i) {
      float4 z = *(const float4*)&Z[(long)(rbase + i) * 128 + kc];
      zv[i][0] = z.x; zv[i][1] = z.y; zv[i][2] = z.z; zv[i][3] = z.w;
    }
#pragma unroll
    for (int kk = 0; kk < 4; ++kk) {
      float4 w = *(const float4*)&wlds[(kc + kk) * 128 + c0];
#pragma unroll
      for (int i = 0; i < 8; ++i) {
        float z = zv[i][kk];
        acc[i][0] += z * w.x; acc[i][1] += z * w.y;
        acc[i][2] += z * w.z; acc[i][3] += z * w.w;
      }
    }
  }

  float4 b = *(const float4*)&B[c0];
  float s[4] = {0.f, 0.f, 0.f, 0.f};
  float s2[4] = {0.f, 0.f, 0.f, 0.f};
#pragma unroll
  for (int i = 0; i < 8; ++i) {
    float4 o;
    o.x = acc[i][0] + b.x; o.y = acc[i][1] + b.y;
    o.z = acc[i][2] + b.z; o.w = acc[i][3] + b.w;
    *(float4*)&Out[(long)(rbase + i) * 128 + c0] = o;
    s[0] += o.x; s[1] += o.y; s[2] += o.z; s[3] += o.w;
    s2[0] += o.x * o.x; s2[1] += o.y * o.y; s2[2] += o.z * o.z; s2[3] += o.w * o.w;
  }
#pragma unroll
  for (int j = 0; j < 4; ++j) {
    atomicAdd(&bnstat[c0 + j], s[j]);
    atomicAdd(&bnstat[128 + c0 + j], s2[j]);
  }
}

// ================= BN apply + relu + final [128x2] matmul =================
__global__ __launch_bounds__(256) void bn_final(
    const float* __restrict__ ZC, const float* __restrict__ bnstat,
    const float* __restrict__ gma, const float* __restrict__ bta,
    const float* __restrict__ W2, const float* __restrict__ B2, float* __restrict__ out)
{
  __shared__ float scl[128], shf[128];
  int tid = threadIdx.x;
  if (tid < 128) {
    float mu = bnstat[tid] * (1.f / NGRAPH);
    float var = bnstat[128 + tid] * (1.f / NGRAPH) - mu * mu;
    float rs = rsqrtf(var + 1e-5f);
    float sc = gma[tid] * rs;
    scl[tid] = sc;
    shf[tid] = bta[tid] - mu * sc;
  }
  __syncthreads();
  int g = blockIdx.x * 256 + tid;
  if (g >= NGRAPH) return;
  float a0 = B2[0], a1 = B2[1];
#pragma unroll 4
  for (int h = 0; h < 128; ++h) {
    float zn = ZC[(long)g * 128 + h] * scl[h] + shf[h];
    zn = fmaxf(zn, 0.f);
    a0 += zn * W2[2 * h];
    a1 += zn * W2[2 * h + 1];
  }
  out[2 * g] = a0;
  out[2 * g + 1] = a1;
}

extern "C" void kernel_launch(void* const* d_in, const int* in_sizes, int n_in,
                              void* d_out, int out_size, void* d_ws, size_t ws_size,
                              hipStream_t stream)
{
  const float* x    = (const float*)d_in[0];
  const int*   ei   = (const int*)d_in[1];
  const int*   batch = (const int*)d_in[3];
  const float* g1w1 = (const float*)d_in[4];  const float* g1b1 = (const float*)d_in[5];
  const float* g1w2 = (const float*)d_in[6];  const float* g1b2 = (const float*)d_in[7];
  const float* g2w1 = (const float*)d_in[8];  const float* g2b1 = (const float*)d_in[9];
  const float* g2w2 = (const float*)d_in[10]; const float* g2b2 = (const float*)d_in[11];
  const float* g3w1 = (const float*)d_in[12]; const float* g3b1 = (const float*)d_in[13];
  const float* g3w2 = (const float*)d_in[14]; const float* g3b2 = (const float*)d_in[15];
  const float* jkw  = (const float*)d_in[16]; const float* jkb  = (const float*)d_in[17];
  const float* c1w  = (const float*)d_in[18]; const float* c1b  = (const float*)d_in[19];
  const float* bng  = (const float*)d_in[20]; const float* bnb  = (const float*)d_in[21];
  const float* c2w  = (const float*)d_in[22]; const float* c2b  = (const float*)d_in[23];

  const int N = in_sizes[3];
  const int E = in_sizes[1] / 2;
  const int* src = ei;
  const int* dst = ei + E;

  char* w = (char*)d_ws;
  auto alloc = [&](size_t bytes) {
    char* p = w;
    w += (bytes + 255) & ~(size_t)255;
    return p;
  };
  _Float16* hA = (_Float16*)alloc((size_t)N * 128 * 2);   // layer-3 out
  _Float16* hB = (_Float16*)alloc((size_t)N * 128 * 2);   // layer-2 out
  _Float16* hC = (_Float16*)alloc((size_t)N * 128 * 2);   // layer-1 out
  _Float16* x8h = (_Float16*)alloc((size_t)N * 8 * 2);
  float* P       = (float*)alloc((size_t)NGRAPH * 384 * 4);
  float* cnt     = (float*)alloc((size_t)NGRAPH * 4);
  float* bnstat  = (float*)alloc(256 * 4);
  float* gbuf = (float*)alloc((size_t)NGRAPH * 128 * 4);
  float* zc   = (float*)alloc((size_t)NGRAPH * 128 * 4);
  // deg, scanst contiguous -> one memset
  int* deg      = (int*)alloc((size_t)N * 4);
  unsigned* scanst = (unsigned*)alloc((size_t)1024 * 4);
  int* cursor   = (int*)alloc((size_t)N * 4);
  int* rowstart = (int*)alloc((size_t)(N + 1) * 4);
  int* eidx     = (int*)alloc((size_t)E * 4);
  int* gstart   = (int*)alloc((size_t)(NGRAPH + 1) * 4);
  _Float16* wtbuf = (_Float16*)alloc((size_t)5 * 2 * 16384 * 2);

  _Float16* WThi[5];
  _Float16* WTlo[5];
  for (int m = 0; m < 5; ++m) {
    WThi[m] = wtbuf + (size_t)m * 2 * 16384;
    WTlo[m] = WThi[m] + 16384;
  }

  const int nchunk = (N + 255) / 256;
  const int eb = (E + 255) / 256;

  // ---- memset deg+scanst (contiguous allocs incl. padding) ----
  hipMemsetAsync(deg, 0, (size_t)((char*)(scanst + 1024) - (char*)deg), stream);

  // ---- merged hist + weight prep(fp16 hi/lo) + x pad + zero(bnstat) + graph bounds ----
  {
    WPs p;
    p.w[0] = g1w2; p.w[1] = g2w1; p.w[2] = g2w2; p.w[3] = g3w1; p.w[4] = g3w2;
    for (int m = 0; m < 5; ++m) { p.hi[m] = WThi[m]; p.lo[m] = WTlo[m]; }
    int total = E + 5 * 16384 + N * 8 + 256 + N;
    prep_hist<<<(total + 255) / 256, 256, 0, stream>>>(p, x, x8h, N, dst, deg, E,
                                                       batch, gstart, bnstat);
  }

  // ---- single-pass scan (writes rowstart + cursor) + fill ----
  scan_onepass<<<nchunk, 256, 0, stream>>>(deg, rowstart, cursor, scanst, N, E, nchunk);
  fill_eidx<<<eb, 256, 0, stream>>>(src, dst, cursor, eidx, E);

  const int fBlocks = (N + 63) / 64;

  // ---- layers (re-fused; f16-MFMA weights) ----
  fused_l1<<<fBlocks, 256, 0, stream>>>(x8h, rowstart, eidx, g1w1, g1b1,
      WThi[0], WTlo[0], g1b2, hC, N);
  fused_gin<<<fBlocks, 256, 0, stream>>>(hC, rowstart, eidx,
      WThi[1], WTlo[1], g2b1, WThi[2], WTlo[2], g2b2, hB, N);
  fused_gin<<<fBlocks, 256, 0, stream>>>(hB, rowstart, eidx,
      WThi[3], WTlo[3], g3b1, WThi[4], WTlo[4], g3b2, hA, N);

  // ---- pooling: one block per graph, no atomics ----
  pool_direct<<<NGRAPH, 256, 0, stream>>>(hC, hB, hA, gstart, P, cnt);

  // ---- head ----
  jk_gemm<<<NGRAPH / 2, 256, 0, stream>>>(P, cnt, jkw, jkb, gbuf);
  gemm_bn<<<NGRAPH / 64, 256, 0, stream>>>(gbuf, c1w, c1b, zc, bnstat, NGRAPH);
  bn_final<<<(NGRAPH + 255) / 256, 256, 0, stream>>>(zc, bnstat, bng, bnb, c2w, c2b, (float*)d_out);
}